// Round 5
// baseline (244.878 us; speedup 1.0000x reference)
//
#include <hip/hip_runtime.h>
#include <stdint.h>

#define F 128
#define KNB 16
#define TWO_F 256
#define ROWS 64          // rows per block (4 waves x 16 rows)
#define THREADS 256
#define HSTR 133         // f32 stride of LN scratch rows (spread banks)
#define LN_EPS 1e-5f
#define NEG_SLOPE 0.2f

typedef unsigned short u16;
typedef __bf16 bf16x8 __attribute__((ext_vector_type(8)));
typedef float f32x4 __attribute__((ext_vector_type(4)));

union BF8 { bf16x8 v; u16 us[8]; uint4 u4; };

__device__ __forceinline__ float b2f(u16 u) {
    union { float f; uint32_t i; } v; v.i = ((uint32_t)u) << 16; return v.f;
}
__device__ __forceinline__ u16 f2b(float f) {
    union { float f; uint32_t i; } v; v.f = f;
    uint32_t r = (v.i + 0x7FFFu + ((v.i >> 16) & 1u)) >> 16;
    return (u16)r;
}

// 8 f32 -> 8 bf16 per thread
extern "C" __global__ void cast_f32_bf16(const float* __restrict__ src,
                                         u16* __restrict__ dst, int n8) {
    const int i = blockIdx.x * blockDim.x + threadIdx.x;
    if (i >= n8) return;
    const float4* s = (const float4*)src + (size_t)i * 2;
    const float4 a = s[0], b = s[1];
    BF8 o;
    o.us[0] = f2b(a.x); o.us[1] = f2b(a.y); o.us[2] = f2b(a.z); o.us[3] = f2b(a.w);
    o.us[4] = f2b(b.x); o.us[5] = f2b(b.y); o.us[6] = f2b(b.z); o.us[7] = f2b(b.w);
    ((uint4*)dst)[i] = o.u4;
}

// Register-direct front-end with 4-neighbor batched gather (explicit load temps
// force ~16 loads in flight per wave; accumulate order identical to verified
// kernel). Verified LDS epilogue with wave-local sync.
// Lane (ln15, quad) owns A-row = blk*64 + wave*16 + ln15, k-slice quad*8 (+32j).
// C/D layout (verified): col = lane&15, row = quad*4 + reg.
template <int FEAT_BF, int W_BF>
__global__ __launch_bounds__(THREADS, 4)
void gnn_fused(const float* __restrict__ feat_f32, const u16* __restrict__ feat_bf,
               const int* __restrict__ adj,
               const float* __restrict__ W_f32, const u16* __restrict__ W_bf,
               const float* __restrict__ bias, const float* __restrict__ gamma,
               const float* __restrict__ beta,
               float* __restrict__ out, int N)
{
    __shared__ float hb[ROWS * HSTR];   // 34048 B LN scratch (per-wave regions)

    const int tid  = threadIdx.x;
    const int wave = tid >> 6;
    const int lane = tid & 63;
    const int ln15 = lane & 15;
    const int quad = lane >> 4;
    const int fb   = quad * 8;          // k sub-offset within each 32-chunk
    const int rb   = wave * 16;

    const long rowA  = (long)blockIdx.x * ROWS + rb + ln15;
    const bool rok   = rowA < (long)N;
    const long rsafe = rok ? rowA : 0;

    // ---- adjacency: hoist all 16 ids to registers (4x int4, one 64B line) ----
    int idx[16];
    {
        const int4* ap = (const int4*)(adj + rsafe * KNB);
        const int4 a0 = ap[0], a1 = ap[1], a2 = ap[2], a3 = ap[3];
        idx[0]  = a0.x; idx[1]  = a0.y; idx[2]  = a0.z; idx[3]  = a0.w;
        idx[4]  = a1.x; idx[5]  = a1.y; idx[6]  = a1.z; idx[7]  = a1.w;
        idx[8]  = a2.x; idx[9]  = a2.y; idx[10] = a2.z; idx[11] = a2.w;
        idx[12] = a3.x; idx[13] = a3.y; idx[14] = a3.z; idx[15] = a3.w;
    }

    // ---- neighbor gather-mean: 4-neighbor batched loads, in-order accumulate ----
    float acc[32];
    #pragma unroll
    for (int t = 0; t < 32; ++t) acc[t] = 0.f;
    int cnt = 0;

    if (rok) {
        if (FEAT_BF) {
            #pragma unroll
            for (int kk = 0; kk < KNB; kk += 4) {
                // issue all 16 loads of this batch (clamped addr; accumulate is guarded)
                uint4 u0[4], u1[4], u2[4], u3[4];
                {
                    const int i0 = idx[kk + 0], i1 = idx[kk + 1];
                    const int i2 = idx[kk + 2], i3 = idx[kk + 3];
                    const u16* n0 = feat_bf + (size_t)((i0 >= 0 && i0 < N) ? i0 : 0) * F + fb;
                    const u16* n1 = feat_bf + (size_t)((i1 >= 0 && i1 < N) ? i1 : 0) * F + fb;
                    const u16* n2 = feat_bf + (size_t)((i2 >= 0 && i2 < N) ? i2 : 0) * F + fb;
                    const u16* n3 = feat_bf + (size_t)((i3 >= 0 && i3 < N) ? i3 : 0) * F + fb;
                    #pragma unroll
                    for (int j = 0; j < 4; ++j) u0[j] = *(const uint4*)(n0 + j * 32);
                    #pragma unroll
                    for (int j = 0; j < 4; ++j) u1[j] = *(const uint4*)(n1 + j * 32);
                    #pragma unroll
                    for (int j = 0; j < 4; ++j) u2[j] = *(const uint4*)(n2 + j * 32);
                    #pragma unroll
                    for (int j = 0; j < 4; ++j) u3[j] = *(const uint4*)(n3 + j * 32);
                }
                // accumulate in k-ascending order (bit-identical to verified loop)
                #pragma unroll
                for (int k2 = 0; k2 < 4; ++k2) {
                    const int id = idx[kk + k2];
                    if (id >= 0 && id < N) {
                        ++cnt;
                        const uint4* uk = (k2 == 0) ? u0 : (k2 == 1) ? u1 : (k2 == 2) ? u2 : u3;
                        #pragma unroll
                        for (int j = 0; j < 4; ++j) {
                            BF8 u; u.u4 = uk[j];
                            #pragma unroll
                            for (int t = 0; t < 8; ++t) acc[j * 8 + t] += b2f(u.us[t]);
                        }
                    }
                }
            }
        } else {
            for (int k = 0; k < KNB; ++k) {
                const int id = idx[k];
                if (id >= 0 && id < N) {
                    ++cnt;
                    const float* nb = feat_f32 + (size_t)id * F + fb;
                    #pragma unroll
                    for (int j = 0; j < 4; ++j) {
                        const float4 p0 = *(const float4*)(nb + j * 32);
                        const float4 p1 = *(const float4*)(nb + j * 32 + 4);
                        acc[j * 8 + 0] += p0.x; acc[j * 8 + 1] += p0.y;
                        acc[j * 8 + 2] += p0.z; acc[j * 8 + 3] += p0.w;
                        acc[j * 8 + 4] += p1.x; acc[j * 8 + 5] += p1.y;
                        acc[j * 8 + 6] += p1.z; acc[j * 8 + 7] += p1.w;
                    }
                }
            }
        }
    }
    const float scale = 1.f / (float)(cnt > 0 ? cnt : 1);

    // ---- own features -> A-frag (ks 0..3): after gather (frees regs during gather) ----
    bf16x8 afrag[8];
    if (FEAT_BF) {
        const u16* orow = feat_bf + rsafe * F + fb;
        #pragma unroll
        for (int j = 0; j < 4; ++j)
            afrag[j] = *(const bf16x8*)(orow + j * 32);
    } else {
        const float* orow = feat_f32 + rsafe * F + fb;
        #pragma unroll
        for (int j = 0; j < 4; ++j) {
            const float4 p0 = *(const float4*)(orow + j * 32);
            const float4 p1 = *(const float4*)(orow + j * 32 + 4);
            BF8 o;
            o.us[0] = f2b(p0.x); o.us[1] = f2b(p0.y); o.us[2] = f2b(p0.z); o.us[3] = f2b(p0.w);
            o.us[4] = f2b(p1.x); o.us[5] = f2b(p1.y); o.us[6] = f2b(p1.z); o.us[7] = f2b(p1.w);
            afrag[j] = o.v;
        }
    }

    // mean half (ks 4..7)
    #pragma unroll
    for (int j = 0; j < 4; ++j) {
        BF8 o;
        #pragma unroll
        for (int t = 0; t < 8; ++t) o.us[t] = f2b(acc[j * 8 + t] * scale);
        afrag[4 + j] = o.v;
    }

    // ---- GEMM: h[16 x 128] per wave via mfma 16x16x32 bf16, W streamed from L2 ----
    f32x4 accf[8];
    #pragma unroll
    for (int c = 0; c < 8; ++c) accf[c] = (f32x4){0.f, 0.f, 0.f, 0.f};

    #pragma unroll
    for (int ks = 0; ks < 8; ++ks) {
        #pragma unroll
        for (int c = 0; c < 8; ++c) {
            bf16x8 bfrag;
            if (W_BF) {
                bfrag = *(const bf16x8*)(W_bf + (size_t)(c * 16 + ln15) * TWO_F + fb + ks * 32);
            } else {
                const float* wr = W_f32 + (size_t)(c * 16 + ln15) * TWO_F + fb + ks * 32;
                const float4 a = *(const float4*)wr, b = *(const float4*)(wr + 4);
                BF8 o;
                o.us[0] = f2b(a.x); o.us[1] = f2b(a.y); o.us[2] = f2b(a.z); o.us[3] = f2b(a.w);
                o.us[4] = f2b(b.x); o.us[5] = f2b(b.y); o.us[6] = f2b(b.z); o.us[7] = f2b(b.w);
                bfrag = o.v;
            }
            accf[c] = __builtin_amdgcn_mfma_f32_16x16x32_bf16(afrag[ks], bfrag, accf[c], 0, 0, 0);
        }
    }

    // ---- verified epilogue: h -> per-wave LDS region, LN with 4 lanes/row ----
    float bval[8];
    #pragma unroll
    for (int c = 0; c < 8; ++c) bval[c] = bias[c * 16 + ln15];

    #pragma unroll
    for (int c = 0; c < 8; ++c) {
        #pragma unroll
        for (int t = 0; t < 4; ++t) {
            const int rr = quad * 4 + t;
            hb[(rb + rr) * HSTR + c * 16 + ln15] = accf[c][t] + bval[c];
        }
    }
    // hb region is strictly per-wave: wave-local LDS drain suffices (no block barrier).
    asm volatile("s_waitcnt lgkmcnt(0)" ::: "memory");
    __builtin_amdgcn_sched_barrier(0);

    const int er = lane >> 2;                  // row 0..15 within wave slice
    const int eq = lane & 3;                   // 32-col slice
    const float* hr = hb + (rb + er) * HSTR + eq * 32;
    float sum = 0.f, sq = 0.f;
    #pragma unroll
    for (int t = 0; t < 32; ++t) { const float v = hr[t]; sum += v; sq += v * v; }
    sum += __shfl_xor(sum, 1); sq += __shfl_xor(sq, 1);
    sum += __shfl_xor(sum, 2); sq += __shfl_xor(sq, 2);

    const float mu   = sum * (1.f / 128.f);
    const float var  = sq * (1.f / 128.f) - mu * mu;
    const float rsig = rsqrtf(fmaxf(var, 0.f) + LN_EPS);

    const long org = (long)blockIdx.x * ROWS + rb + er;
    if (org < N) {
        const int cb = eq * 32;
        float* orow = out + org * F + cb;
        #pragma unroll
        for (int j = 0; j < 8; ++j) {
            const float4 g  = *(const float4*)(gamma + cb + j * 4);
            const float4 bt = *(const float4*)(beta  + cb + j * 4);
            float4 o;
            o.x = (hr[j * 4 + 0] - mu) * rsig * g.x + bt.x;
            o.y = (hr[j * 4 + 1] - mu) * rsig * g.y + bt.y;
            o.z = (hr[j * 4 + 2] - mu) * rsig * g.z + bt.z;
            o.w = (hr[j * 4 + 3] - mu) * rsig * g.w + bt.w;
            o.x = (o.x >= 0.f) ? o.x : NEG_SLOPE * o.x;
            o.y = (o.y >= 0.f) ? o.y : NEG_SLOPE * o.y;
            o.z = (o.z >= 0.f) ? o.z : NEG_SLOPE * o.z;
            o.w = (o.w >= 0.f) ? o.w : NEG_SLOPE * o.w;
            *(float4*)(orow + j * 4) = o;
        }
    }
}

extern "C" void kernel_launch(void* const* d_in, const int* in_sizes, int n_in,
                              void* d_out, int out_size, void* d_ws, size_t ws_size,
                              hipStream_t stream) {
    const float* feat  = (const float*)d_in[0];
    const int*   adj   = (const int*)d_in[1];
    const float* W     = (const float*)d_in[2];
    const float* bias  = (const float*)d_in[3];
    const float* gamma = (const float*)d_in[4];
    const float* beta  = (const float*)d_in[5];
    float* out = (float*)d_out;

    const int N = in_sizes[0] / F;
    const size_t needW = (size_t)TWO_F * F * sizeof(u16);        // 65536 B
    const size_t needF = (size_t)N * F * sizeof(u16);            // ~25.6 MB
    u16* wsW = (u16*)d_ws;
    u16* wsF = (u16*)((char*)d_ws + needW);

    const int mode = (ws_size >= needW + needF) ? 2 : (ws_size >= needW ? 1 : 0);

    if (mode >= 1) {
        const int n8 = TWO_F * F / 8;
        cast_f32_bf16<<<dim3((n8 + 255) / 256), dim3(256), 0, stream>>>(W, wsW, n8);
    }
    if (mode == 2) {
        const int n8 = N * F / 8;   // N*F divisible by 8
        cast_f32_bf16<<<dim3((n8 + 255) / 256), dim3(256), 0, stream>>>(feat, wsF, n8);
    }

    const int blocks = (N + ROWS - 1) / ROWS;
    if (mode == 2) {
        gnn_fused<1, 1><<<dim3(blocks), dim3(THREADS), 0, stream>>>(feat, wsF, adj, W, wsW, bias, gamma, beta, out, N);
    } else if (mode == 1) {
        gnn_fused<0, 1><<<dim3(blocks), dim3(THREADS), 0, stream>>>(feat, wsF, adj, W, wsW, bias, gamma, beta, out, N);
    } else {
        gnn_fused<0, 0><<<dim3(blocks), dim3(THREADS), 0, stream>>>(feat, wsF, adj, W, wsW, bias, gamma, beta, out, N);
    }
}

// Round 7
// 243.512 us; speedup vs baseline: 1.0056x; 1.0056x over previous
//
#include <hip/hip_runtime.h>
#include <stdint.h>

#define F 128
#define KNB 16
#define TWO_F 256
#define ROWS 64          // rows per block (4 waves x 16 rows)
#define THREADS 256
#define HSTR 133         // f32 stride of LN scratch rows (spread banks)
#define LN_EPS 1e-5f
#define NEG_SLOPE 0.2f

typedef unsigned short u16;
typedef __bf16 bf16x8 __attribute__((ext_vector_type(8)));
typedef float f32x4 __attribute__((ext_vector_type(4)));

union BF8 { bf16x8 v; u16 us[8]; uint4 u4; };

__device__ __forceinline__ float b2f(u16 u) {
    union { float f; uint32_t i; } v; v.i = ((uint32_t)u) << 16; return v.f;
}
__device__ __forceinline__ u16 f2b(float f) {
    union { float f; uint32_t i; } v; v.f = f;
    uint32_t r = (v.i + 0x7FFFu + ((v.i >> 16) & 1u)) >> 16;
    return (u16)r;
}

// 8 f32 -> 8 bf16 per thread
extern "C" __global__ void cast_f32_bf16(const float* __restrict__ src,
                                         u16* __restrict__ dst, int n8) {
    const int i = blockIdx.x * blockDim.x + threadIdx.x;
    if (i >= n8) return;
    const float4* s = (const float4*)src + (size_t)i * 2;
    const float4 a = s[0], b = s[1];
    BF8 o;
    o.us[0] = f2b(a.x); o.us[1] = f2b(a.y); o.us[2] = f2b(a.z); o.us[3] = f2b(a.w);
    o.us[4] = f2b(b.x); o.us[5] = f2b(b.y); o.us[6] = f2b(b.z); o.us[7] = f2b(b.w);
    ((uint4*)dst)[i] = o.u4;
}

// ---- standalone gather kernel: one thread per (row, 32-feature quarter) ----
// No LDS, no MFMA state -> high occupancy on the latency-bound phase.
// Accumulation order bit-identical to the verified fused gather.
extern "C" __global__ __launch_bounds__(256, 5)
void gather_mean(const u16* __restrict__ feat_bf, const int* __restrict__ adj,
                 u16* __restrict__ mean_bf, int N)
{
    const int gt  = blockIdx.x * 256 + threadIdx.x;
    const int row = gt >> 2;
    if (row >= N) return;
    const int fb = (gt & 3) * 32;                 // 32 contiguous features (64B)

    int idx[16];
    {
        const int4* ap = (const int4*)(adj + (size_t)row * KNB);
        const int4 a0 = ap[0], a1 = ap[1], a2 = ap[2], a3 = ap[3];
        idx[0]  = a0.x; idx[1]  = a0.y; idx[2]  = a0.z; idx[3]  = a0.w;
        idx[4]  = a1.x; idx[5]  = a1.y; idx[6]  = a1.z; idx[7]  = a1.w;
        idx[8]  = a2.x; idx[9]  = a2.y; idx[10] = a2.z; idx[11] = a2.w;
        idx[12] = a3.x; idx[13] = a3.y; idx[14] = a3.z; idx[15] = a3.w;
    }

    float acc[32];
    #pragma unroll
    for (int t = 0; t < 32; ++t) acc[t] = 0.f;
    int cnt = 0;

    for (int k = 0; k < KNB; ++k) {
        const int id = idx[k];
        if (id >= 0 && id < N) {
            ++cnt;
            const u16* nb = feat_bf + (size_t)id * F + fb;
            #pragma unroll
            for (int j = 0; j < 4; ++j) {
                BF8 u; u.u4 = *(const uint4*)(nb + j * 8);   // contiguous 16B steps
                #pragma unroll
                for (int t = 0; t < 8; ++t) acc[j * 8 + t] += b2f(u.us[t]);
            }
        }
    }

    const float scale = 1.f / (float)(cnt > 0 ? cnt : 1);
    uint4* dst = (uint4*)(mean_bf + (size_t)row * F + fb);
    #pragma unroll
    for (int j = 0; j < 4; ++j) {
        BF8 o;
        #pragma unroll
        for (int t = 0; t < 8; ++t) o.us[t] = f2b(acc[j * 8 + t] * scale);
        dst[j] = o.u4;
    }
}

// ---- split GEMM+LN kernel: round-4 verified kernel with gather replaced by
// a linear mean load from ws. ----
extern "C" __global__ __launch_bounds__(THREADS, 4)
void gnn_split(const u16* __restrict__ feat_bf, const u16* __restrict__ mean_bf,
               const u16* __restrict__ W_bf,
               const float* __restrict__ bias, const float* __restrict__ gamma,
               const float* __restrict__ beta,
               float* __restrict__ out, int N)
{
    __shared__ float hb[ROWS * HSTR];   // 34048 B LN scratch (per-wave regions)

    const int tid  = threadIdx.x;
    const int wave = tid >> 6;
    const int lane = tid & 63;
    const int ln15 = lane & 15;
    const int quad = lane >> 4;
    const int fb   = quad * 8;          // k sub-offset within each 32-chunk
    const int rb   = wave * 16;

    const long rowA  = (long)blockIdx.x * ROWS + rb + ln15;
    const bool rok   = rowA < (long)N;
    const long rsafe = rok ? rowA : 0;

    // A fragments: own (ks 0..3) + precomputed mean (ks 4..7), both linear loads
    bf16x8 afrag[8];
    {
        const u16* orow = feat_bf + rsafe * F + fb;
        const u16* mrow = mean_bf + rsafe * F + fb;
        #pragma unroll
        for (int j = 0; j < 4; ++j) afrag[j]     = *(const bf16x8*)(orow + j * 32);
        #pragma unroll
        for (int j = 0; j < 4; ++j) afrag[4 + j] = *(const bf16x8*)(mrow + j * 32);
    }

    // GEMM: h[16 x 128] per wave via mfma 16x16x32 bf16, W streamed from L2
    f32x4 accf[8];
    #pragma unroll
    for (int c = 0; c < 8; ++c) accf[c] = (f32x4){0.f, 0.f, 0.f, 0.f};

    #pragma unroll
    for (int ks = 0; ks < 8; ++ks) {
        #pragma unroll
        for (int c = 0; c < 8; ++c) {
            const bf16x8 bfrag = *(const bf16x8*)(W_bf + (size_t)(c * 16 + ln15) * TWO_F + fb + ks * 32);
            accf[c] = __builtin_amdgcn_mfma_f32_16x16x32_bf16(afrag[ks], bfrag, accf[c], 0, 0, 0);
        }
    }

    // verified epilogue: h -> per-wave LDS region, LN with 4 lanes/row
    float bval[8];
    #pragma unroll
    for (int c = 0; c < 8; ++c) bval[c] = bias[c * 16 + ln15];

    #pragma unroll
    for (int c = 0; c < 8; ++c) {
        #pragma unroll
        for (int t = 0; t < 4; ++t) {
            const int rr = quad * 4 + t;
            hb[(rb + rr) * HSTR + c * 16 + ln15] = accf[c][t] + bval[c];
        }
    }
    // hb is strictly per-wave: wave-local LDS drain suffices (no block barrier)
    asm volatile("s_waitcnt lgkmcnt(0)" ::: "memory");
    __builtin_amdgcn_sched_barrier(0);

    const int er = lane >> 2;
    const int eq = lane & 3;
    const float* hr = hb + (rb + er) * HSTR + eq * 32;
    float sum = 0.f, sq = 0.f;
    #pragma unroll
    for (int t = 0; t < 32; ++t) { const float v = hr[t]; sum += v; sq += v * v; }
    sum += __shfl_xor(sum, 1); sq += __shfl_xor(sq, 1);
    sum += __shfl_xor(sum, 2); sq += __shfl_xor(sq, 2);

    const float mu   = sum * (1.f / 128.f);
    const float var  = sq * (1.f / 128.f) - mu * mu;
    const float rsig = rsqrtf(fmaxf(var, 0.f) + LN_EPS);

    const long org = (long)blockIdx.x * ROWS + rb + er;
    if (org < N) {
        const int cb = eq * 32;
        float* orow = out + org * F + cb;
        #pragma unroll
        for (int j = 0; j < 8; ++j) {
            const float4 g  = *(const float4*)(gamma + cb + j * 4);
            const float4 bt = *(const float4*)(beta  + cb + j * 4);
            float4 o;
            o.x = (hr[j * 4 + 0] - mu) * rsig * g.x + bt.x;
            o.y = (hr[j * 4 + 1] - mu) * rsig * g.y + bt.y;
            o.z = (hr[j * 4 + 2] - mu) * rsig * g.z + bt.z;
            o.w = (hr[j * 4 + 3] - mu) * rsig * g.w + bt.w;
            o.x = (o.x >= 0.f) ? o.x : NEG_SLOPE * o.x;
            o.y = (o.y >= 0.f) ? o.y : NEG_SLOPE * o.y;
            o.z = (o.z >= 0.f) ? o.z : NEG_SLOPE * o.z;
            o.w = (o.w >= 0.f) ? o.w : NEG_SLOPE * o.w;
            *(float4*)(orow + j * 4) = o;
        }
    }
}

// ---- round-4 fused kernel, kept verbatim as fallback when ws is too small ----
template <int FEAT_BF, int W_BF>
__global__ __launch_bounds__(THREADS, 4)
void gnn_fused(const float* __restrict__ feat_f32, const u16* __restrict__ feat_bf,
               const int* __restrict__ adj,
               const float* __restrict__ W_f32, const u16* __restrict__ W_bf,
               const float* __restrict__ bias, const float* __restrict__ gamma,
               const float* __restrict__ beta,
               float* __restrict__ out, int N)
{
    __shared__ float hb[ROWS * HSTR];

    const int tid  = threadIdx.x;
    const int wave = tid >> 6;
    const int lane = tid & 63;
    const int ln15 = lane & 15;
    const int quad = lane >> 4;
    const int fb   = quad * 8;
    const int rb   = wave * 16;

    const long rowA  = (long)blockIdx.x * ROWS + rb + ln15;
    const bool rok   = rowA < (long)N;
    const long rsafe = rok ? rowA : 0;

    int idx[16];
    {
        const int4* ap = (const int4*)(adj + rsafe * KNB);
        const int4 a0 = ap[0], a1 = ap[1], a2 = ap[2], a3 = ap[3];
        idx[0]  = a0.x; idx[1]  = a0.y; idx[2]  = a0.z; idx[3]  = a0.w;
        idx[4]  = a1.x; idx[5]  = a1.y; idx[6]  = a1.z; idx[7]  = a1.w;
        idx[8]  = a2.x; idx[9]  = a2.y; idx[10] = a2.z; idx[11] = a2.w;
        idx[12] = a3.x; idx[13] = a3.y; idx[14] = a3.z; idx[15] = a3.w;
    }

    bf16x8 afrag[8];
    if (FEAT_BF) {
        const u16* orow = feat_bf + rsafe * F + fb;
        #pragma unroll
        for (int j = 0; j < 4; ++j)
            afrag[j] = *(const bf16x8*)(orow + j * 32);
    } else {
        const float* orow = feat_f32 + rsafe * F + fb;
        #pragma unroll
        for (int j = 0; j < 4; ++j) {
            const float4 p0 = *(const float4*)(orow + j * 32);
            const float4 p1 = *(const float4*)(orow + j * 32 + 4);
            BF8 o;
            o.us[0] = f2b(p0.x); o.us[1] = f2b(p0.y); o.us[2] = f2b(p0.z); o.us[3] = f2b(p0.w);
            o.us[4] = f2b(p1.x); o.us[5] = f2b(p1.y); o.us[6] = f2b(p1.z); o.us[7] = f2b(p1.w);
            afrag[j] = o.v;
        }
    }

    float acc[32];
    #pragma unroll
    for (int t = 0; t < 32; ++t) acc[t] = 0.f;
    int cnt = 0;

    if (rok) {
        for (int k = 0; k < KNB; ++k) {
            const int id = idx[k];
            if (id >= 0 && id < N) {
                ++cnt;
                if (FEAT_BF) {
                    const u16* nb = feat_bf + (size_t)id * F + fb;
                    #pragma unroll
                    for (int j = 0; j < 4; ++j) {
                        BF8 u; u.u4 = *(const uint4*)(nb + j * 32);
                        #pragma unroll
                        for (int t = 0; t < 8; ++t) acc[j * 8 + t] += b2f(u.us[t]);
                    }
                } else {
                    const float* nb = feat_f32 + (size_t)id * F + fb;
                    #pragma unroll
                    for (int j = 0; j < 4; ++j) {
                        const float4 p0 = *(const float4*)(nb + j * 32);
                        const float4 p1 = *(const float4*)(nb + j * 32 + 4);
                        acc[j * 8 + 0] += p0.x; acc[j * 8 + 1] += p0.y;
                        acc[j * 8 + 2] += p0.z; acc[j * 8 + 3] += p0.w;
                        acc[j * 8 + 4] += p1.x; acc[j * 8 + 5] += p1.y;
                        acc[j * 8 + 6] += p1.z; acc[j * 8 + 7] += p1.w;
                    }
                }
            }
        }
    }
    const float scale = 1.f / (float)(cnt > 0 ? cnt : 1);

    #pragma unroll
    for (int j = 0; j < 4; ++j) {
        BF8 o;
        #pragma unroll
        for (int t = 0; t < 8; ++t) o.us[t] = f2b(acc[j * 8 + t] * scale);
        afrag[4 + j] = o.v;
    }

    f32x4 accf[8];
    #pragma unroll
    for (int c = 0; c < 8; ++c) accf[c] = (f32x4){0.f, 0.f, 0.f, 0.f};

    #pragma unroll
    for (int ks = 0; ks < 8; ++ks) {
        #pragma unroll
        for (int c = 0; c < 8; ++c) {
            bf16x8 bfrag;
            if (W_BF) {
                bfrag = *(const bf16x8*)(W_bf + (size_t)(c * 16 + ln15) * TWO_F + fb + ks * 32);
            } else {
                const float* wr = W_f32 + (size_t)(c * 16 + ln15) * TWO_F + fb + ks * 32;
                const float4 a = *(const float4*)wr, b = *(const float4*)(wr + 4);
                BF8 o;
                o.us[0] = f2b(a.x); o.us[1] = f2b(a.y); o.us[2] = f2b(a.z); o.us[3] = f2b(a.w);
                o.us[4] = f2b(b.x); o.us[5] = f2b(b.y); o.us[6] = f2b(b.z); o.us[7] = f2b(b.w);
                bfrag = o.v;
            }
            accf[c] = __builtin_amdgcn_mfma_f32_16x16x32_bf16(afrag[ks], bfrag, accf[c], 0, 0, 0);
        }
    }

    float bval[8];
    #pragma unroll
    for (int c = 0; c < 8; ++c) bval[c] = bias[c * 16 + ln15];

    #pragma unroll
    for (int c = 0; c < 8; ++c) {
        #pragma unroll
        for (int t = 0; t < 4; ++t) {
            const int rr = quad * 4 + t;
            hb[(rb + rr) * HSTR + c * 16 + ln15] = accf[c][t] + bval[c];
        }
    }
    asm volatile("s_waitcnt lgkmcnt(0)" ::: "memory");
    __builtin_amdgcn_sched_barrier(0);

    const int er = lane >> 2;
    const int eq = lane & 3;
    const float* hr = hb + (rb + er) * HSTR + eq * 32;
    float sum = 0.f, sq = 0.f;
    #pragma unroll
    for (int t = 0; t < 32; ++t) { const float v = hr[t]; sum += v; sq += v * v; }
    sum += __shfl_xor(sum, 1); sq += __shfl_xor(sq, 1);
    sum += __shfl_xor(sum, 2); sq += __shfl_xor(sq, 2);

    const float mu   = sum * (1.f / 128.f);
    const float var  = sq * (1.f / 128.f) - mu * mu;
    const float rsig = rsqrtf(fmaxf(var, 0.f) + LN_EPS);

    const long org = (long)blockIdx.x * ROWS + rb + er;
    if (org < N) {
        const int cb = eq * 32;
        float* orow = out + org * F + cb;
        #pragma unroll
        for (int j = 0; j < 8; ++j) {
            const float4 g  = *(const float4*)(gamma + cb + j * 4);
            const float4 bt = *(const float4*)(beta  + cb + j * 4);
            float4 o;
            o.x = (hr[j * 4 + 0] - mu) * rsig * g.x + bt.x;
            o.y = (hr[j * 4 + 1] - mu) * rsig * g.y + bt.y;
            o.z = (hr[j * 4 + 2] - mu) * rsig * g.z + bt.z;
            o.w = (hr[j * 4 + 3] - mu) * rsig * g.w + bt.w;
            o.x = (o.x >= 0.f) ? o.x : NEG_SLOPE * o.x;
            o.y = (o.y >= 0.f) ? o.y : NEG_SLOPE * o.y;
            o.z = (o.z >= 0.f) ? o.z : NEG_SLOPE * o.z;
            o.w = (o.w >= 0.f) ? o.w : NEG_SLOPE * o.w;
            *(float4*)(orow + j * 4) = o;
        }
    }
}

extern "C" void kernel_launch(void* const* d_in, const int* in_sizes, int n_in,
                              void* d_out, int out_size, void* d_ws, size_t ws_size,
                              hipStream_t stream) {
    const float* feat  = (const float*)d_in[0];
    const int*   adj   = (const int*)d_in[1];
    const float* W     = (const float*)d_in[2];
    const float* bias  = (const float*)d_in[3];
    const float* gamma = (const float*)d_in[4];
    const float* beta  = (const float*)d_in[5];
    float* out = (float*)d_out;

    const int N = in_sizes[0] / F;
    const size_t needW = (size_t)TWO_F * F * sizeof(u16);        // 65536 B
    const size_t needF = (size_t)N * F * sizeof(u16);            // ~25.6 MB
    const size_t needM = (size_t)N * F * sizeof(u16);            // ~25.6 MB
    u16* wsW = (u16*)d_ws;
    u16* wsF = (u16*)((char*)d_ws + needW);
    u16* wsM = (u16*)((char*)d_ws + needW + needF);

    const int blocks = (N + ROWS - 1) / ROWS;

    if (ws_size >= needW + needF + needM) {
        // split path: cast W + feat, standalone high-occupancy gather, then GEMM+LN
        const int n8w = TWO_F * F / 8;
        cast_f32_bf16<<<dim3((n8w + 255) / 256), dim3(256), 0, stream>>>(W, wsW, n8w);
        const int n8f = N * F / 8;
        cast_f32_bf16<<<dim3((n8f + 255) / 256), dim3(256), 0, stream>>>(feat, wsF, n8f);
        const int gth = N * 4;
        gather_mean<<<dim3((gth + 255) / 256), dim3(256), 0, stream>>>(wsF, adj, wsM, N);
        gnn_split<<<dim3(blocks), dim3(THREADS), 0, stream>>>(wsF, wsM, wsW, bias, gamma, beta, out, N);
        return;
    }

    // fallback: round-4 fused path
    const int mode = (ws_size >= needW + needF) ? 2 : (ws_size >= needW ? 1 : 0);
    if (mode >= 1) {
        const int n8 = TWO_F * F / 8;
        cast_f32_bf16<<<dim3((n8 + 255) / 256), dim3(256), 0, stream>>>(W, wsW, n8);
    }
    if (mode == 2) {
        const int n8 = N * F / 8;
        cast_f32_bf16<<<dim3((n8 + 255) / 256), dim3(256), 0, stream>>>(feat, wsF, n8);
    }
    if (mode == 2) {
        gnn_fused<1, 1><<<dim3(blocks), dim3(THREADS), 0, stream>>>(feat, wsF, adj, W, wsW, bias, gamma, beta, out, N);
    } else if (mode == 1) {
        gnn_fused<0, 1><<<dim3(blocks), dim3(THREADS), 0, stream>>>(feat, wsF, adj, W, wsW, bias, gamma, beta, out, N);
    } else {
        gnn_fused<0, 0><<<dim3(blocks), dim3(THREADS), 0, stream>>>(feat, wsF, adj, W, wsW, bias, gamma, beta, out, N);
    }
}

// Round 8
// 234.400 us; speedup vs baseline: 1.0447x; 1.0389x over previous
//
#include <hip/hip_runtime.h>
#include <stdint.h>

#define F 128
#define KNB 16
#define TWO_F 256
#define ROWS 64          // rows per block (4 waves x 16 rows)
#define THREADS 256
#define HSTR 133         // f32 stride of LN scratch rows (spread banks)
#define LN_EPS 1e-5f
#define NEG_SLOPE 0.2f

typedef unsigned short u16;
typedef __bf16 bf16x8 __attribute__((ext_vector_type(8)));
typedef float f32x4 __attribute__((ext_vector_type(4)));

union BF8 { bf16x8 v; u16 us[8]; uint4 u4; };

__device__ __forceinline__ float b2f(u16 u) {
    union { float f; uint32_t i; } v; v.i = ((uint32_t)u) << 16; return v.f;
}
__device__ __forceinline__ u16 f2b(float f) {
    union { float f; uint32_t i; } v; v.f = f;
    uint32_t r = (v.i + 0x7FFFu + ((v.i >> 16) & 1u)) >> 16;
    return (u16)r;
}

// accumulate 8 bf16 (packed in uint4) into acc[0..7] — inlined, constant indices
__device__ __forceinline__ void acc8(float* acc, uint4 u) {
    BF8 b; b.u4 = u;
    #pragma unroll
    for (int t = 0; t < 8; ++t) acc[t] += b2f(b.us[t]);
}

// 8 f32 -> 8 bf16 per thread
extern "C" __global__ void cast_f32_bf16(const float* __restrict__ src,
                                         u16* __restrict__ dst, int n8) {
    const int i = blockIdx.x * blockDim.x + threadIdx.x;
    if (i >= n8) return;
    const float4* s = (const float4*)src + (size_t)i * 2;
    const float4 a = s[0], b = s[1];
    BF8 o;
    o.us[0] = f2b(a.x); o.us[1] = f2b(a.y); o.us[2] = f2b(a.z); o.us[3] = f2b(a.w);
    o.us[4] = f2b(b.x); o.us[5] = f2b(b.y); o.us[6] = f2b(b.z); o.us[7] = f2b(b.w);
    ((uint4*)dst)[i] = o.u4;
}

// Fused kernel, round-4 verified structure. Gather rewritten for memory-level
// parallelism: unconditional clamped loads in statically-indexed batches of 8
// neighbors (x2 adjacent 64B slices = one 128B line each), accumulate guarded
// by a validity bitmask. Per-element summation order is k-ascending —
// bit-identical to the verified kernel.
// Lane (ln15, quad) owns A-row = blk*64 + wave*16 + ln15, k-slice quad*8.
// C/D layout (verified): col = lane&15, row = quad*4 + reg.
template <int FEAT_BF, int W_BF>
__global__ __launch_bounds__(THREADS, 4)
void gnn_fused(const float* __restrict__ feat_f32, const u16* __restrict__ feat_bf,
               const int* __restrict__ adj,
               const float* __restrict__ W_f32, const u16* __restrict__ W_bf,
               const float* __restrict__ bias, const float* __restrict__ gamma,
               const float* __restrict__ beta,
               float* __restrict__ out, int N)
{
    __shared__ float hb[ROWS * HSTR];   // 34048 B LN scratch (per-wave regions)

    const int tid  = threadIdx.x;
    const int wave = tid >> 6;
    const int lane = tid & 63;
    const int ln15 = lane & 15;
    const int quad = lane >> 4;
    const int fb   = quad * 8;          // k sub-offset within each 32-chunk
    const int rb   = wave * 16;

    const long rowA  = (long)blockIdx.x * ROWS + rb + ln15;
    const bool rok   = rowA < (long)N;
    const long rsafe = rok ? rowA : 0;

    // ---- adjacency: hoist all 16 ids to registers (4x int4, one 64B line) ----
    int idx[16];
    {
        const int4* ap = (const int4*)(adj + rsafe * KNB);
        const int4 a0 = ap[0], a1 = ap[1], a2 = ap[2], a3 = ap[3];
        idx[0]  = a0.x; idx[1]  = a0.y; idx[2]  = a0.z; idx[3]  = a0.w;
        idx[4]  = a1.x; idx[5]  = a1.y; idx[6]  = a1.z; idx[7]  = a1.w;
        idx[8]  = a2.x; idx[9]  = a2.y; idx[10] = a2.z; idx[11] = a2.w;
        idx[12] = a3.x; idx[13] = a3.y; idx[14] = a3.z; idx[15] = a3.w;
    }

    // ---- validity mask + clamped element offsets (once) ----
    int off[16];
    uint32_t okm = 0;
    int cnt = 0;
    #pragma unroll
    for (int k = 0; k < KNB; ++k) {
        const bool v = rok && (idx[k] >= 0) && (idx[k] < N);
        okm |= (v ? 1u : 0u) << k;
        cnt += v ? 1 : 0;
        off[k] = (v ? idx[k] : 0) * F;
    }
    const float scale = 1.f / (float)(cnt > 0 ? cnt : 1);

    bf16x8 afrag[8];

    // ---- gather-mean with forced MLP (bf16 path) ----
    if (FEAT_BF) {
        #pragma unroll
        for (int jh = 0; jh < 2; ++jh) {
            const int jb = fb + jh * 64;          // element offset of slice pair
            float acc[16];
            #pragma unroll
            for (int t = 0; t < 16; ++t) acc[t] = 0.f;

            uint4 va[8], vb[8];
            // batch 1: k = 0..7 — issue all 16 loads unconditionally
            #pragma unroll
            for (int k = 0; k < 8; ++k) {
                const u16* p = feat_bf + (size_t)off[k] + jb;
                va[k] = *(const uint4*)p;
                vb[k] = *(const uint4*)(p + 32);
            }
            #pragma unroll
            for (int k = 0; k < 8; ++k) {
                if (okm & (1u << k)) { acc8(acc, va[k]); acc8(acc + 8, vb[k]); }
            }
            // batch 2: k = 8..15
            #pragma unroll
            for (int k = 0; k < 8; ++k) {
                const u16* p = feat_bf + (size_t)off[k + 8] + jb;
                va[k] = *(const uint4*)p;
                vb[k] = *(const uint4*)(p + 32);
            }
            #pragma unroll
            for (int k = 0; k < 8; ++k) {
                if (okm & (1u << (k + 8))) { acc8(acc, va[k]); acc8(acc + 8, vb[k]); }
            }

            BF8 oA, oB;
            #pragma unroll
            for (int t = 0; t < 8; ++t) {
                oA.us[t] = f2b(acc[t] * scale);
                oB.us[t] = f2b(acc[8 + t] * scale);
            }
            afrag[4 + 2 * jh] = oA.v;
            afrag[5 + 2 * jh] = oB.v;
        }
    } else {
        // f32 fallback path (verified round-4 branchy gather)
        float acc[32];
        #pragma unroll
        for (int t = 0; t < 32; ++t) acc[t] = 0.f;
        if (rok) {
            for (int k = 0; k < KNB; ++k) {
                const int id = idx[k];
                if (id >= 0 && id < N) {
                    const float* nb = feat_f32 + (size_t)id * F + fb;
                    #pragma unroll
                    for (int j = 0; j < 4; ++j) {
                        const float4 p0 = *(const float4*)(nb + j * 32);
                        const float4 p1 = *(const float4*)(nb + j * 32 + 4);
                        acc[j * 8 + 0] += p0.x; acc[j * 8 + 1] += p0.y;
                        acc[j * 8 + 2] += p0.z; acc[j * 8 + 3] += p0.w;
                        acc[j * 8 + 4] += p1.x; acc[j * 8 + 5] += p1.y;
                        acc[j * 8 + 6] += p1.z; acc[j * 8 + 7] += p1.w;
                    }
                }
            }
        }
        #pragma unroll
        for (int j = 0; j < 4; ++j) {
            BF8 o;
            #pragma unroll
            for (int t = 0; t < 8; ++t) o.us[t] = f2b(acc[j * 8 + t] * scale);
            afrag[4 + j] = o.v;
        }
    }

    // ---- own features -> A-frag (ks 0..3): after gather (frees regs there) ----
    if (FEAT_BF) {
        const u16* orow = feat_bf + rsafe * F + fb;
        #pragma unroll
        for (int j = 0; j < 4; ++j)
            afrag[j] = *(const bf16x8*)(orow + j * 32);
    } else {
        const float* orow = feat_f32 + rsafe * F + fb;
        #pragma unroll
        for (int j = 0; j < 4; ++j) {
            const float4 p0 = *(const float4*)(orow + j * 32);
            const float4 p1 = *(const float4*)(orow + j * 32 + 4);
            BF8 o;
            o.us[0] = f2b(p0.x); o.us[1] = f2b(p0.y); o.us[2] = f2b(p0.z); o.us[3] = f2b(p0.w);
            o.us[4] = f2b(p1.x); o.us[5] = f2b(p1.y); o.us[6] = f2b(p1.z); o.us[7] = f2b(p1.w);
            afrag[j] = o.v;
        }
    }

    // ---- GEMM: h[16 x 128] per wave via mfma 16x16x32 bf16, W streamed from L2 ----
    f32x4 accf[8];
    #pragma unroll
    for (int c = 0; c < 8; ++c) accf[c] = (f32x4){0.f, 0.f, 0.f, 0.f};

    #pragma unroll
    for (int ks = 0; ks < 8; ++ks) {
        #pragma unroll
        for (int c = 0; c < 8; ++c) {
            bf16x8 bfrag;
            if (W_BF) {
                bfrag = *(const bf16x8*)(W_bf + (size_t)(c * 16 + ln15) * TWO_F + fb + ks * 32);
            } else {
                const float* wr = W_f32 + (size_t)(c * 16 + ln15) * TWO_F + fb + ks * 32;
                const float4 a = *(const float4*)wr, b = *(const float4*)(wr + 4);
                BF8 o;
                o.us[0] = f2b(a.x); o.us[1] = f2b(a.y); o.us[2] = f2b(a.z); o.us[3] = f2b(a.w);
                o.us[4] = f2b(b.x); o.us[5] = f2b(b.y); o.us[6] = f2b(b.z); o.us[7] = f2b(b.w);
                bfrag = o.v;
            }
            accf[c] = __builtin_amdgcn_mfma_f32_16x16x32_bf16(afrag[ks], bfrag, accf[c], 0, 0, 0);
        }
    }

    // ---- verified epilogue: h -> per-wave LDS region, LN with 4 lanes/row ----
    float bval[8];
    #pragma unroll
    for (int c = 0; c < 8; ++c) bval[c] = bias[c * 16 + ln15];

    #pragma unroll
    for (int c = 0; c < 8; ++c) {
        #pragma unroll
        for (int t = 0; t < 4; ++t) {
            const int rr = quad * 4 + t;
            hb[(rb + rr) * HSTR + c * 16 + ln15] = accf[c][t] + bval[c];
        }
    }
    // hb region is strictly per-wave: wave-local LDS drain suffices (no block barrier)
    asm volatile("s_waitcnt lgkmcnt(0)" ::: "memory");
    __builtin_amdgcn_sched_barrier(0);

    const int er = lane >> 2;                  // row 0..15 within wave slice
    const int eq = lane & 3;                   // 32-col slice
    const float* hr = hb + (rb + er) * HSTR + eq * 32;
    float sum = 0.f, sq = 0.f;
    #pragma unroll
    for (int t = 0; t < 32; ++t) { const float v = hr[t]; sum += v; sq += v * v; }
    sum += __shfl_xor(sum, 1); sq += __shfl_xor(sq, 1);
    sum += __shfl_xor(sum, 2); sq += __shfl_xor(sq, 2);

    const float mu   = sum * (1.f / 128.f);
    const float var  = sq * (1.f / 128.f) - mu * mu;
    const float rsig = rsqrtf(fmaxf(var, 0.f) + LN_EPS);

    const long org = (long)blockIdx.x * ROWS + rb + er;
    if (org < N) {
        const int cb = eq * 32;
        float* orow = out + org * F + cb;
        #pragma unroll
        for (int j = 0; j < 8; ++j) {
            const float4 g  = *(const float4*)(gamma + cb + j * 4);
            const float4 bt = *(const float4*)(beta  + cb + j * 4);
            float4 o;
            o.x = (hr[j * 4 + 0] - mu) * rsig * g.x + bt.x;
            o.y = (hr[j * 4 + 1] - mu) * rsig * g.y + bt.y;
            o.z = (hr[j * 4 + 2] - mu) * rsig * g.z + bt.z;
            o.w = (hr[j * 4 + 3] - mu) * rsig * g.w + bt.w;
            o.x = (o.x >= 0.f) ? o.x : NEG_SLOPE * o.x;
            o.y = (o.y >= 0.f) ? o.y : NEG_SLOPE * o.y;
            o.z = (o.z >= 0.f) ? o.z : NEG_SLOPE * o.z;
            o.w = (o.w >= 0.f) ? o.w : NEG_SLOPE * o.w;
            *(float4*)(orow + j * 4) = o;
        }
    }
}

extern "C" void kernel_launch(void* const* d_in, const int* in_sizes, int n_in,
                              void* d_out, int out_size, void* d_ws, size_t ws_size,
                              hipStream_t stream) {
    const float* feat  = (const float*)d_in[0];
    const int*   adj   = (const int*)d_in[1];
    const float* W     = (const float*)d_in[2];
    const float* bias  = (const float*)d_in[3];
    const float* gamma = (const float*)d_in[4];
    const float* beta  = (const float*)d_in[5];
    float* out = (float*)d_out;

    const int N = in_sizes[0] / F;
    const size_t needW = (size_t)TWO_F * F * sizeof(u16);        // 65536 B
    const size_t needF = (size_t)N * F * sizeof(u16);            // ~25.6 MB
    u16* wsW = (u16*)d_ws;
    u16* wsF = (u16*)((char*)d_ws + needW);

    const int mode = (ws_size >= needW + needF) ? 2 : (ws_size >= needW ? 1 : 0);

    if (mode >= 1) {
        const int n8 = TWO_F * F / 8;
        cast_f32_bf16<<<dim3((n8 + 255) / 256), dim3(256), 0, stream>>>(W, wsW, n8);
    }
    if (mode == 2) {
        const int n8 = N * F / 8;   // N*F divisible by 8
        cast_f32_bf16<<<dim3((n8 + 255) / 256), dim3(256), 0, stream>>>(feat, wsF, n8);
    }

    const int blocks = (N + ROWS - 1) / ROWS;
    if (mode == 2) {
        gnn_fused<1, 1><<<dim3(blocks), dim3(THREADS), 0, stream>>>(feat, wsF, adj, W, wsW, bias, gamma, beta, out, N);
    } else if (mode == 1) {
        gnn_fused<0, 1><<<dim3(blocks), dim3(THREADS), 0, stream>>>(feat, wsF, adj, W, wsW, bias, gamma, beta, out, N);
    } else {
        gnn_fused<0, 0><<<dim3(blocks), dim3(THREADS), 0, stream>>>(feat, wsF, adj, W, wsW, bias, gamma, beta, out, N);
    }
}

// Round 9
// 204.195 us; speedup vs baseline: 1.1992x; 1.1479x over previous
//
#include <hip/hip_runtime.h>
#include <stdint.h>

#define F 128
#define KNB 16
#define TWO_F 256
#define ROWS 64          // rows per block
#define THREADS 256
#define XSTRIDE 264      // bf16 elems per x row (256 + 8 pad)
#define HSTR 133         // f32 stride of LN scratch rows (spread banks)
#define LN_EPS 1e-5f
#define NEG_SLOPE 0.2f

typedef unsigned short u16;
typedef __bf16 bf16x8 __attribute__((ext_vector_type(8)));
typedef float f32x4 __attribute__((ext_vector_type(4)));

union BF8 { bf16x8 v; u16 us[8]; uint4 u4; };

__device__ __forceinline__ float b2f(u16 u) {
    union { float f; uint32_t i; } v; v.i = ((uint32_t)u) << 16; return v.f;
}
__device__ __forceinline__ u16 f2b(float f) {
    union { float f; uint32_t i; } v; v.f = f;
    uint32_t r = (v.i + 0x7FFFu + ((v.i >> 16) & 1u)) >> 16;
    return (u16)r;
}

// accumulate 8 bf16 (packed in uint4) into acc[0..7] — constant indices after inline
__device__ __forceinline__ void acc8(float* acc, uint4 u) {
    BF8 b; b.u4 = u;
    #pragma unroll
    for (int t = 0; t < 8; ++t) acc[t] += b2f(b.us[t]);
}

// 8 f32 -> 8 bf16 per thread
extern "C" __global__ void cast_f32_bf16(const float* __restrict__ src,
                                         u16* __restrict__ dst, int n8) {
    const int i = blockIdx.x * blockDim.x + threadIdx.x;
    if (i >= n8) return;
    const float4* s = (const float4*)src + (size_t)i * 2;
    const float4 a = s[0], b = s[1];
    BF8 o;
    o.us[0] = f2b(a.x); o.us[1] = f2b(a.y); o.us[2] = f2b(a.z); o.us[3] = f2b(a.w);
    o.us[4] = f2b(b.x); o.us[5] = f2b(b.y); o.us[6] = f2b(b.z); o.us[7] = f2b(b.w);
    ((uint4*)dst)[i] = o.u4;
}

// Round-0 champion structure (LDS x-tile staging, 4 barriers, hb overlay) with:
//  (1) batched unconditional-load gather (mask-guarded, bit-identical order)
//  (2) coalesced output stores (col = j*32 + eq*8: eq-group writes contiguous 128B)
// MODE 0: all fp32 from global.  MODE 1: W from bf16 ws.  MODE 2: W + feat bf16 ws.
template <int MODE>
__global__ __launch_bounds__(THREADS, 4)
void gnn_fused(const float* __restrict__ feat_f32, const u16* __restrict__ feat_bf,
               const int* __restrict__ adj,
               const float* __restrict__ W_f32, const u16* __restrict__ W_bf,
               const float* __restrict__ bias, const float* __restrict__ gamma,
               const float* __restrict__ beta,
               float* __restrict__ out, int N)
{
    __shared__ __align__(16) char smem[ROWS * XSTRIDE * 2 + ROWS * KNB * 4]; // 37888 B
    u16* xs   = (u16*)smem;                              // [64][264] bf16 x-tile
    int* adjs = (int*)(smem + ROWS * XSTRIDE * 2);       // [64][16]
    float* hb = (float*)smem;                            // epilogue overlay [64][HSTR] f32

    const int tid = threadIdx.x;
    const long block0 = (long)blockIdx.x * ROWS;

    // ---- stage adjacency tile (1024 ints, 4 per thread) ----
    {
        const int flat = tid * 4;
        const long base = block0 * KNB + flat;
        const long total = (long)N * KNB;
        if (base + 3 < total) {
            *(int4*)(adjs + flat) = *(const int4*)(adj + base);
        } else {
            for (int j = 0; j < 4; ++j)
                adjs[flat + j] = (base + j < total) ? (int)adj[base + j] : -1;
        }
    }
    __syncthreads();

    // ---- prologue: x = [own_feats | masked neighbor mean] as bf16 in LDS ----
    {
        const int r  = tid >> 2;          // row in tile 0..63
        const int q4 = tid & 3;           // 32-feature slice
        const long rg = block0 + r;
        const int fbase = q4 * 32;
        u16* xrow = xs + r * XSTRIDE;

        if (rg < N) {
            // own features
            if (MODE == 2) {
                const uint4* src = (const uint4*)(feat_bf + rg * F + fbase);
                uint4* dst = (uint4*)(xrow + fbase);
                #pragma unroll
                for (int j = 0; j < 4; ++j) dst[j] = src[j];
            } else {
                const float4* s = (const float4*)(feat_f32 + rg * F + fbase);
                uint4* dst = (uint4*)(xrow + fbase);
                #pragma unroll
                for (int j = 0; j < 4; ++j) {
                    const float4 a = s[j * 2], b = s[j * 2 + 1];
                    BF8 o;
                    o.us[0] = f2b(a.x); o.us[1] = f2b(a.y); o.us[2] = f2b(a.z); o.us[3] = f2b(a.w);
                    o.us[4] = f2b(b.x); o.us[5] = f2b(b.y); o.us[6] = f2b(b.z); o.us[7] = f2b(b.w);
                    dst[j] = o.u4;
                }
            }

            // neighbor gather-mean (fp32 accumulate)
            float acc[32];
            #pragma unroll
            for (int t = 0; t < 32; ++t) acc[t] = 0.f;
            int cnt = 0;

            if (MODE == 2) {
                // hoist idx from LDS adjs into registers
                int idxr[16];
                {
                    const int4* ap = (const int4*)(adjs + r * KNB);
                    const int4 A0 = ap[0], A1 = ap[1], A2 = ap[2], A3 = ap[3];
                    idxr[0]  = A0.x; idxr[1]  = A0.y; idxr[2]  = A0.z; idxr[3]  = A0.w;
                    idxr[4]  = A1.x; idxr[5]  = A1.y; idxr[6]  = A1.z; idxr[7]  = A1.w;
                    idxr[8]  = A2.x; idxr[9]  = A2.y; idxr[10] = A2.z; idxr[11] = A2.w;
                    idxr[12] = A3.x; idxr[13] = A3.y; idxr[14] = A3.z; idxr[15] = A3.w;
                }
                int off[16];
                uint32_t okm = 0;
                #pragma unroll
                for (int k = 0; k < KNB; ++k) {
                    const bool v = (idxr[k] >= 0) && (idxr[k] < N);
                    okm |= (v ? 1u : 0u) << k;
                    cnt += v ? 1 : 0;
                    off[k] = (v ? idxr[k] : 0) * F;
                }
                // batched unconditional loads (4 nbrs x 4 uint4), mask-guarded accumulate
                #pragma unroll
                for (int kk = 0; kk < KNB; kk += 4) {
                    uint4 c0[4], c1[4], c2[4], c3[4];
                    #pragma unroll
                    for (int k2 = 0; k2 < 4; ++k2) {
                        const uint4* p = (const uint4*)(feat_bf + (size_t)off[kk + k2] + fbase);
                        c0[k2] = p[0]; c1[k2] = p[1]; c2[k2] = p[2]; c3[k2] = p[3];
                    }
                    #pragma unroll
                    for (int k2 = 0; k2 < 4; ++k2) {
                        if (okm & (1u << (kk + k2))) {
                            acc8(acc,      c0[k2]); acc8(acc + 8,  c1[k2]);
                            acc8(acc + 16, c2[k2]); acc8(acc + 24, c3[k2]);
                        }
                    }
                }
            } else {
                for (int k = 0; k < KNB; ++k) {
                    const int idx = adjs[r * KNB + k];
                    if (idx >= 0 && idx < N) {
                        ++cnt;
                        const float4* ns = (const float4*)(feat_f32 + (long)idx * F + fbase);
                        #pragma unroll
                        for (int j = 0; j < 8; ++j) {
                            const float4 a = ns[j];
                            acc[j * 4 + 0] += a.x; acc[j * 4 + 1] += a.y;
                            acc[j * 4 + 2] += a.z; acc[j * 4 + 3] += a.w;
                        }
                    }
                }
            }

            const float scale = 1.f / (float)(cnt > 0 ? cnt : 1);
            uint4* mdst = (uint4*)(xrow + F + fbase);
            #pragma unroll
            for (int j = 0; j < 4; ++j) {
                BF8 o;
                #pragma unroll
                for (int t = 0; t < 8; ++t) o.us[t] = f2b(acc[j * 8 + t] * scale);
                mdst[j] = o.u4;
            }
        } else {
            const uint4 z = make_uint4(0, 0, 0, 0);
            uint4* d0 = (uint4*)(xrow + fbase);
            uint4* d1 = (uint4*)(xrow + F + fbase);
            #pragma unroll
            for (int j = 0; j < 4; ++j) { d0[j] = z; d1[j] = z; }
        }
    }
    __syncthreads();

    // ---- GEMM: each wave computes h[16 rows x 128 cols] via mfma 16x16x32 bf16 ----
    const int wave = tid >> 6;
    const int lane = tid & 63;
    const int ln15 = lane & 15;
    const int quad = lane >> 4;
    const int rb   = wave * 16;

    f32x4 accf[8];
    #pragma unroll
    for (int c = 0; c < 8; ++c) accf[c] = (f32x4){0.f, 0.f, 0.f, 0.f};

    const u16* arow = xs + (rb + ln15) * XSTRIDE + quad * 8;

    #pragma unroll
    for (int ks = 0; ks < 8; ++ks) {
        const bf16x8 afrag = *(const bf16x8*)(arow + ks * 32);
        #pragma unroll
        for (int c = 0; c < 8; ++c) {
            bf16x8 bfrag;
            if (MODE >= 1) {
                bfrag = *(const bf16x8*)(W_bf + (size_t)(c * 16 + ln15) * TWO_F + quad * 8 + ks * 32);
            } else {
                const float* wr = W_f32 + (size_t)(c * 16 + ln15) * TWO_F + quad * 8 + ks * 32;
                const float4 a = *(const float4*)wr, b = *(const float4*)(wr + 4);
                BF8 o;
                o.us[0] = f2b(a.x); o.us[1] = f2b(a.y); o.us[2] = f2b(a.z); o.us[3] = f2b(a.w);
                o.us[4] = f2b(b.x); o.us[5] = f2b(b.y); o.us[6] = f2b(b.z); o.us[7] = f2b(b.w);
                bfrag = o.v;
            }
            accf[c] = __builtin_amdgcn_mfma_f32_16x16x32_bf16(afrag, bfrag, accf[c], 0, 0, 0);
        }
    }

    // bias per (col-tile, lane-col)
    float bval[8];
    #pragma unroll
    for (int c = 0; c < 8; ++c) bval[c] = bias[c * 16 + ln15];

    // xs no longer needed; overlay hb (crosses wave regions -> barrier first)
    __syncthreads();

    // ---- write h to LDS scratch (C/D layout: col = lane&15, row = quad*4 + reg) ----
    #pragma unroll
    for (int c = 0; c < 8; ++c) {
        #pragma unroll
        for (int t = 0; t < 4; ++t) {
            const int rr = quad * 4 + t;
            hb[(rb + rr) * HSTR + c * 16 + ln15] = accf[c][t] + bval[c];
        }
    }
    __syncthreads();

    // ---- LayerNorm + LeakyReLU: 4 lanes per row ----
    const int er = lane >> 2;                  // row 0..15 (within wave slice)
    const int eq = lane & 3;                   // 32-col slice (stats only)
    const float* hr = hb + (rb + er) * HSTR + eq * 32;
    float sum = 0.f, sq = 0.f;
    #pragma unroll
    for (int t = 0; t < 32; ++t) { const float v = hr[t]; sum += v; sq += v * v; }
    sum += __shfl_xor(sum, 1); sq += __shfl_xor(sq, 1);
    sum += __shfl_xor(sum, 2); sq += __shfl_xor(sq, 2);

    const float mu   = sum * (1.f / 128.f);
    const float var  = sq * (1.f / 128.f) - mu * mu;
    const float rsig = rsqrtf(fmaxf(var, 0.f) + LN_EPS);

    const long org = block0 + rb + er;
    if (org < N) {
        // coalesced stores: lane (er,eq) writes cols [j*32 + eq*8, +8) — each
        // 4-lane eq-group covers a contiguous 128B segment per j.
        const float* hrow = hb + (rb + er) * HSTR;
        float* orow = out + org * F;
        #pragma unroll
        for (int j = 0; j < 4; ++j) {
            const int cb2 = j * 32 + eq * 8;
            const float4 g0 = *(const float4*)(gamma + cb2);
            const float4 g1 = *(const float4*)(gamma + cb2 + 4);
            const float4 b0 = *(const float4*)(beta  + cb2);
            const float4 b1 = *(const float4*)(beta  + cb2 + 4);
            const float* hp = hrow + cb2;
            float4 o0, o1;
            o0.x = (hp[0] - mu) * rsig * g0.x + b0.x;
            o0.y = (hp[1] - mu) * rsig * g0.y + b0.y;
            o0.z = (hp[2] - mu) * rsig * g0.z + b0.z;
            o0.w = (hp[3] - mu) * rsig * g0.w + b0.w;
            o1.x = (hp[4] - mu) * rsig * g1.x + b1.x;
            o1.y = (hp[5] - mu) * rsig * g1.y + b1.y;
            o1.z = (hp[6] - mu) * rsig * g1.z + b1.z;
            o1.w = (hp[7] - mu) * rsig * g1.w + b1.w;
            o0.x = (o0.x >= 0.f) ? o0.x : NEG_SLOPE * o0.x;
            o0.y = (o0.y >= 0.f) ? o0.y : NEG_SLOPE * o0.y;
            o0.z = (o0.z >= 0.f) ? o0.z : NEG_SLOPE * o0.z;
            o0.w = (o0.w >= 0.f) ? o0.w : NEG_SLOPE * o0.w;
            o1.x = (o1.x >= 0.f) ? o1.x : NEG_SLOPE * o1.x;
            o1.y = (o1.y >= 0.f) ? o1.y : NEG_SLOPE * o1.y;
            o1.z = (o1.z >= 0.f) ? o1.z : NEG_SLOPE * o1.z;
            o1.w = (o1.w >= 0.f) ? o1.w : NEG_SLOPE * o1.w;
            *(float4*)(orow + cb2)     = o0;
            *(float4*)(orow + cb2 + 4) = o1;
        }
    }
}

extern "C" void kernel_launch(void* const* d_in, const int* in_sizes, int n_in,
                              void* d_out, int out_size, void* d_ws, size_t ws_size,
                              hipStream_t stream) {
    const float* feat  = (const float*)d_in[0];
    const int*   adj   = (const int*)d_in[1];
    const float* W     = (const float*)d_in[2];
    const float* bias  = (const float*)d_in[3];
    const float* gamma = (const float*)d_in[4];
    const float* beta  = (const float*)d_in[5];
    float* out = (float*)d_out;

    const int N = in_sizes[0] / F;
    const size_t needW = (size_t)TWO_F * F * sizeof(u16);        // 65536 B
    const size_t needF = (size_t)N * F * sizeof(u16);            // ~25.6 MB
    u16* wsW = (u16*)d_ws;
    u16* wsF = (u16*)((char*)d_ws + needW);

    const int mode = (ws_size >= needW + needF) ? 2 : (ws_size >= needW ? 1 : 0);

    if (mode >= 1) {
        const int n8 = TWO_F * F / 8;
        cast_f32_bf16<<<dim3((n8 + 255) / 256), dim3(256), 0, stream>>>(W, wsW, n8);
    }
    if (mode == 2) {
        const int n8 = N * F / 8;   // N*F divisible by 8
        cast_f32_bf16<<<dim3((n8 + 255) / 256), dim3(256), 0, stream>>>(feat, wsF, n8);
    }

    const int blocks = (N + ROWS - 1) / ROWS;
    if (mode == 2) {
        gnn_fused<2><<<dim3(blocks), dim3(THREADS), 0, stream>>>(feat, wsF, adj, W, wsW, bias, gamma, beta, out, N);
    } else if (mode == 1) {
        gnn_fused<1><<<dim3(blocks), dim3(THREADS), 0, stream>>>(feat, wsF, adj, W, wsW, bias, gamma, beta, out, N);
    } else {
        gnn_fused<0><<<dim3(blocks), dim3(THREADS), 0, stream>>>(feat, wsF, adj, W, wsW, bias, gamma, beta, out, N);
    }
}